// Round 3
// baseline (235.428 us; speedup 1.0000x reference)
//
#include <hip/hip_runtime.h>
#include <cmath>

#define HE 361
#define WE 720
#define LL 37
#define HM 180
#define WM 360
#define KK 32
#define NPTS (HM * WM)
#define EPSF 1e-8f
#define PTSB 8    // model points per tile; 360 % 8 == 0 -> tile never crosses a row
#define TPB  4    // tiles per block (software-pipelined)
#define WE37 (WE * LL)

// out layout: out3d [HM*WM*KK*5] | p_model [HM*WM*KK] | ps_o [HM*WM]
#define OFF1 ((size_t)HM * WM * KK * 5)
#define OFF2 (OFF1 + (size_t)HM * WM * KK)

// ws layout (float units):
#define WS_IY    0
#define WS_TY    180
#define WS_IX    360
#define WS_TX    720
#define WS_LOGPE 1080

__device__ __forceinline__ int upper_bound_g(const float* a, int n, float v) {
    int lo = 0, hi = n;
    while (lo < hi) {
        int m = (lo + hi) >> 1;
        if (a[m] <= v) lo = m + 1; else hi = m;
    }
    return lo;  // searchsorted side='right'
}

__global__ void precompute_kernel(const float* __restrict__ era5_lat,
                                  const float* __restrict__ era5_lon,
                                  const float* __restrict__ model_lat,
                                  const float* __restrict__ model_lon,
                                  const float* __restrict__ p_levels,
                                  int* __restrict__ ws_iy, float* __restrict__ ws_ty,
                                  int* __restrict__ ws_ix, float* __restrict__ ws_tx,
                                  float* __restrict__ ws_logpe) {
    int t = blockIdx.x * blockDim.x + threadIdx.x;
    if (t < HM) {
        float v = model_lat[t];
        int i = upper_bound_g(era5_lat, HE, v) - 1;
        if (i < 0) i = 0;
        if (i > HE - 2) i = HE - 2;
        ws_iy[t] = i;
        ws_ty[t] = (v - era5_lat[i]) / (era5_lat[i + 1] - era5_lat[i]);
    } else if (t < HM + WM) {
        int j = t - HM;
        float v = model_lon[j];
        int i = upper_bound_g(era5_lon, WE, v) - 1;
        if (i < 0) i = 0;
        if (i > WE - 2) i = WE - 2;
        ws_ix[j] = i;
        ws_tx[j] = (v - era5_lon[i]) / (era5_lon[i + 1] - era5_lon[i]);
    } else if (t < HM + WM + LL) {
        int k = t - HM - WM;
        ws_logpe[k] = logf(p_levels[k] + EPSF);
    }
}

struct Geo { int b00; int pt; float tx, ty; };

// Per-tile register load set: 20 main + 4 tail + 4 ps = 28 dword loads.
struct LSet {
    float a00[5], a01[5], a10[5], a11[5];
    float t00, t01, t10, t11;
    float p00, p01, p10, p11;
};

__device__ __forceinline__ Geo geom_load(int tt, int pt_local,
                                         const int* __restrict__ ws_iy,
                                         const float* __restrict__ ws_ty,
                                         const int* __restrict__ ws_ix,
                                         const float* __restrict__ ws_tx) {
    Geo g;
    g.pt = tt * PTSB + pt_local;
    const int y = g.pt / WM;
    const int x = g.pt - y * WM;
    const int iy = ws_iy[y];
    const int ix = ws_ix[x];
    g.ty = ws_ty[y];
    g.tx = ws_tx[x];
    g.b00 = iy * WE + ix;
    return g;
}

__device__ __forceinline__ void issue_loads(const Geo& g, int grp,
                                            const float* __restrict__ u,
                                            const float* __restrict__ v,
                                            const float* __restrict__ w,
                                            const float* __restrict__ T,
                                            const float* __restrict__ q,
                                            const float* __restrict__ ps,
                                            LSet& s) {
    const int base = g.b00 * LL;
    const int i0 = base + grp;          // grp < 32 <= 36: valid level
    const int i1 = i0 + WE37;
#define LD4(slot, S) \
    s.a00[slot] = S[i0];  s.a01[slot] = S[i0 + LL]; \
    s.a10[slot] = S[i1];  s.a11[slot] = S[i1 + LL];
    LD4(0, u) LD4(1, v) LD4(2, w) LD4(3, T) LD4(4, q)
#undef LD4
    // tail: 25 channels (var 0..4, level 32..36) on grp<25; dummy (safe) otherwise
    int tvar = grp / 5;
    int tl   = 32 + (grp - tvar * 5);
    if (grp >= 25) { tvar = 0; tl = 32; }
    const float* ts = (tvar == 0) ? u : (tvar == 1) ? v
                    : (tvar == 2) ? w : (tvar == 3) ? T : q;
    const int ti0 = base + tl;
    const int ti1 = ti0 + WE37;
    s.t00 = ts[ti0]; s.t01 = ts[ti0 + LL];
    s.t10 = ts[ti1]; s.t11 = ts[ti1 + LL];
    // ps quad (broadcast across the 32-lane group; L1/L2-hot)
    s.p00 = ps[g.b00];      s.p01 = ps[g.b00 + 1];
    s.p10 = ps[g.b00 + WE]; s.p11 = ps[g.b00 + WE + 1];
}

template <int BUF>
__device__ __forceinline__ void consume(const Geo& g, const LSet& s, int tt,
                                        int wv, int lane, int pt_local, int grp,
                                        float ak, float bk,
                                        const float2 (*s_tab)[LL],
                                        float (*s_h)[PTSB][5 * LL],
                                        float (*s_out)[2 * KK * 5],
                                        float* __restrict__ out) {
    const float ty = g.ty, tx = g.tx;
    const float omty = 1.0f - ty, omtx = 1.0f - tx;

    // bilinear -> s_h (writer == reader wave: wave-synchronous, in-order LDS)
#pragma unroll
    for (int it = 0; it < 5; it++) {
        const float hv = omty * (omtx * s.a00[it] + tx * s.a01[it]) +
                         ty   * (omtx * s.a10[it] + tx * s.a11[it]);
        s_h[BUF][pt_local][it * LL + grp] = hv;
    }
    {
        const float hv = omty * (omtx * s.t00 + tx * s.t01) +
                         ty   * (omtx * s.t10 + tx * s.t11);
        if (grp < 25) {
            const int tvar = grp / 5;
            const int tl   = 32 + (grp - tvar * 5);
            s_h[BUF][pt_local][tvar * LL + tl] = hv;
        }
    }

    // ps_m computed redundantly on all lanes (no LDS round-trip)
    const float ps_m = omty * (omtx * s.p00 + tx * s.p01) +
                       ty   * (omtx * s.p10 + tx * s.p11);
    if (grp == 0) out[OFF2 + g.pt] = fminf(fmaxf(ps_m, 30000.0f), 110000.0f);

    const float pm = ak + bk * ps_m;
    out[OFF1 + (size_t)g.pt * KK + grp] = pm;    // coalesced per 32-lane group

    const float lpm = logf(pm + EPSF);

    // linear count-scans == searchsorted(side='right') on sorted arrays.
    // 37 independent broadcast ds_read_b64 (no dependent chain).
    int nv = 0, ii = 0;
#pragma unroll
    for (int m = 0; m < LL; m++) {
        const float2 tb = s_tab[wv][m];
        nv += (tb.x <= ps_m) ? 1 : 0;
        if (m >= 1) ii += (tb.y <= lpm) ? 1 : 0;
    }
    int maxi = nv - 2;
    if (maxi < 0) maxi = 0;
    if (ii > maxi) ii = maxi;
    const bool invalid = (nv < 2);

    const float x0 = s_tab[wv][ii].y;
    const float x1 = s_tab[wv][ii + 1].y;
    const float t = (lpm - x0) / (x1 - x0);

    __builtin_amdgcn_wave_barrier();   // compiler ordering fence (no-op HW)

    const int half = lane >> 5;
    float* so = &s_out[wv][half * (KK * 5)];
#pragma unroll
    for (int var = 0; var < 5; var++) {
        const float g0 = s_h[BUF][pt_local][var * LL + ii];
        const float g1 = s_h[BUF][pt_local][var * LL + ii + 1];
        float o = g0 + t * (g1 - g0);
        if (invalid) o = 0.0f;                         // zero BEFORE clip (matches ref)
        if (var == 3) o = fminf(fmaxf(o, 150.0f), 350.0f);
        if (var == 4) o = fminf(fmaxf(o, 0.0f), 0.05f);
        so[grp * 5 + var] = o;                         // gcd(5,32)=1 -> conflict-free
    }

    __builtin_amdgcn_wave_barrier();

    // coalesced flush: wave's 2 points = 320 contiguous floats
    const size_t ob = (size_t)(tt * PTSB + 2 * wv) * (KK * 5);
#pragma unroll
    for (int c = 0; c < 5; c++) {
        out[ob + lane + 64 * c] = s_out[wv][lane + 64 * c];
    }

    __builtin_amdgcn_wave_barrier();   // flush reads ordered before next tile's writes
}

// 4 tiles per block, 2-deep software pipeline, fully wave-synchronous (no __syncthreads).
__global__ void __launch_bounds__(256)
fused_kernel(const float* __restrict__ u, const float* __restrict__ v,
             const float* __restrict__ w, const float* __restrict__ T,
             const float* __restrict__ q, const float* __restrict__ ps,
             const float* __restrict__ p_levels,
             const float* __restrict__ a_k, const float* __restrict__ b_k,
             const int* __restrict__ ws_iy, const float* __restrict__ ws_ty,
             const int* __restrict__ ws_ix, const float* __restrict__ ws_tx,
             const float* __restrict__ ws_logpe,
             float* __restrict__ out) {
    __shared__ float2 s_tab[4][LL];           // per-wave {p_level, logpe}
    __shared__ float  s_h[2][PTSB][5 * LL];   // double-buffered horizontal result
    __shared__ float  s_out[4][2 * KK * 5];   // per-wave store-coalescing buffer

    const int tid      = threadIdx.x;
    const int wv       = tid >> 6;
    const int lane     = tid & 63;
    const int pt_local = tid >> 5;
    const int grp      = tid & 31;

    if (lane < LL) s_tab[wv][lane] = make_float2(p_levels[lane], ws_logpe[lane]);

    const float ak = a_k[grp];
    const float bk = b_k[grp];

    const int tt0 = blockIdx.x * TPB;
    const Geo g0 = geom_load(tt0 + 0, pt_local, ws_iy, ws_ty, ws_ix, ws_tx);
    const Geo g1 = geom_load(tt0 + 1, pt_local, ws_iy, ws_ty, ws_ix, ws_tx);
    const Geo g2 = geom_load(tt0 + 2, pt_local, ws_iy, ws_ty, ws_ix, ws_tx);
    const Geo g3 = geom_load(tt0 + 3, pt_local, ws_iy, ws_ty, ws_ix, ws_tx);

    LSet sA, sB;
    issue_loads(g0, grp, u, v, w, T, q, ps, sA);
    issue_loads(g1, grp, u, v, w, T, q, ps, sB);

    consume<0>(g0, sA, tt0 + 0, wv, lane, pt_local, grp, ak, bk, s_tab, s_h, s_out, out);
    issue_loads(g2, grp, u, v, w, T, q, ps, sA);
    consume<1>(g1, sB, tt0 + 1, wv, lane, pt_local, grp, ak, bk, s_tab, s_h, s_out, out);
    issue_loads(g3, grp, u, v, w, T, q, ps, sB);
    consume<0>(g2, sA, tt0 + 2, wv, lane, pt_local, grp, ak, bk, s_tab, s_h, s_out, out);
    consume<1>(g3, sB, tt0 + 3, wv, lane, pt_local, grp, ak, bk, s_tab, s_h, s_out, out);
}

extern "C" void kernel_launch(void* const* d_in, const int* in_sizes, int n_in,
                              void* d_out, int out_size, void* d_ws, size_t ws_size,
                              hipStream_t stream) {
    const float* u         = (const float*)d_in[0];
    const float* v         = (const float*)d_in[1];
    const float* w         = (const float*)d_in[2];
    const float* T         = (const float*)d_in[3];
    const float* q         = (const float*)d_in[4];
    const float* ps        = (const float*)d_in[5];
    const float* era5_lat  = (const float*)d_in[6];
    const float* era5_lon  = (const float*)d_in[7];
    const float* model_lat = (const float*)d_in[8];
    const float* model_lon = (const float*)d_in[9];
    const float* p_levels  = (const float*)d_in[10];
    const float* a_k       = (const float*)d_in[11];
    const float* b_k       = (const float*)d_in[12];

    float* wsf = (float*)d_ws;
    int*   ws_iy    = (int*)(wsf + WS_IY);
    float* ws_ty    = wsf + WS_TY;
    int*   ws_ix    = (int*)(wsf + WS_IX);
    float* ws_tx    = wsf + WS_TX;
    float* ws_logpe = wsf + WS_LOGPE;

    float* out = (float*)d_out;

    precompute_kernel<<<3, 256, 0, stream>>>(era5_lat, era5_lon, model_lat, model_lon,
                                             p_levels, ws_iy, ws_ty, ws_ix, ws_tx,
                                             ws_logpe);

    const int blocks = NPTS / (PTSB * TPB);   // 2025
    fused_kernel<<<blocks, 256, 0, stream>>>(u, v, w, T, q, ps, p_levels, a_k, b_k,
                                             ws_iy, ws_ty, ws_ix, ws_tx, ws_logpe, out);
}

// Round 4
// 232.884 us; speedup vs baseline: 1.0109x; 1.0109x over previous
//
#include <hip/hip_runtime.h>
#include <cmath>
#include <stdint.h>

#define HE 361
#define WE 720
#define LL 37
#define HM 180
#define WM 360
#define KK 32
#define NPTS (HM * WM)
#define EPSF 1e-8f
#define PTSB 8    // model points per block; 360 % 8 == 0 -> block never crosses a row
#define WE37 (WE * LL)

// out layout: out3d [HM*WM*KK*5] | p_model [HM*WM*KK] | ps_o [HM*WM]
#define OFF1 ((size_t)HM * WM * KK * 5)
#define OFF2 (OFF1 + (size_t)HM * WM * KK)

// ws layout (float units):
#define WS_IY    0
#define WS_TY    180
#define WS_IX    360
#define WS_TX    720
#define WS_LOGPE 1080

// staging geometry: 10 ranges (5 vars x 2 rows), each up to 16 cols * 37 lvls
// = 592 floats + head(<=3) -> <=149 x4 slots. RSTR=150 slots, RFL=600 floats.
#define RSTR 150
#define RFL  600
#define NRANGE 10
#define NSLOT (RSTR * NRANGE)   // 1500
#define NROUND 6                // ceil(1500/256)

__device__ __forceinline__ int upper_bound_g(const float* a, int n, float v) {
    int lo = 0, hi = n;
    while (lo < hi) {
        int m = (lo + hi) >> 1;
        if (a[m] <= v) lo = m + 1; else hi = m;
    }
    return lo;  // searchsorted side='right'
}

__global__ void precompute_kernel(const float* __restrict__ era5_lat,
                                  const float* __restrict__ era5_lon,
                                  const float* __restrict__ model_lat,
                                  const float* __restrict__ model_lon,
                                  const float* __restrict__ p_levels,
                                  int* __restrict__ ws_iy, float* __restrict__ ws_ty,
                                  int* __restrict__ ws_ix, float* __restrict__ ws_tx,
                                  float* __restrict__ ws_logpe) {
    int t = blockIdx.x * blockDim.x + threadIdx.x;
    if (t < HM) {
        float v = model_lat[t];
        int i = upper_bound_g(era5_lat, HE, v) - 1;
        if (i < 0) i = 0;
        if (i > HE - 2) i = HE - 2;
        ws_iy[t] = i;
        ws_ty[t] = (v - era5_lat[i]) / (era5_lat[i + 1] - era5_lat[i]);
    } else if (t < HM + WM) {
        int j = t - HM;
        float v = model_lon[j];
        int i = upper_bound_g(era5_lon, WE, v) - 1;
        if (i < 0) i = 0;
        if (i > WE - 2) i = WE - 2;
        ws_ix[j] = i;
        ws_tx[j] = (v - era5_lon[i]) / (era5_lon[i + 1] - era5_lon[i]);
    } else if (t < HM + WM + LL) {
        int k = t - HM - WM;
        ws_logpe[k] = logf(p_levels[k] + EPSF);
    }
}

// Block = 8 model points of one row. The 8 points' bilinear stencils cover a
// CONTIGUOUS 16-column x 37-level span per (var,row): 2368 B. Stage the 10
// spans into LDS via 16-B global_load_lds (aligned down to 16-B boundary;
// span end provably within array since total length % 4 == 0), then compute.
__global__ void __launch_bounds__(256)
fused_kernel(const float* __restrict__ u, const float* __restrict__ v,
             const float* __restrict__ w, const float* __restrict__ T,
             const float* __restrict__ q, const float* __restrict__ ps,
             const float* __restrict__ p_levels,
             const float* __restrict__ a_k, const float* __restrict__ b_k,
             const int* __restrict__ ws_iy, const float* __restrict__ ws_ty,
             const int* __restrict__ ws_ix, const float* __restrict__ ws_tx,
             const float* __restrict__ ws_logpe,
             float* __restrict__ out) {
    __shared__ float  s_stage[NRANGE * RFL];   // 24000 B
    __shared__ float  s_h[PTSB][5 * LL];       // horizontal interp result
    __shared__ float2 s_tab[4][LL];            // per-wave {p_level, logpe}
    __shared__ float  s_out[4][2 * KK * 5];    // per-wave store-coalescing buffer

    const int tid      = threadIdx.x;
    const int wv       = tid >> 6;
    const int lane     = tid & 63;
    const int pt_local = tid >> 5;
    const int grp      = tid & 31;

    if (lane < LL) s_tab[wv][lane] = make_float2(p_levels[lane], ws_logpe[lane]);

    const int pt0 = blockIdx.x * PTSB;
    const int y   = pt0 / WM;
    const int x0  = pt0 - y * WM;
    const int x   = x0 + pt_local;
    const int pt  = pt0 + pt_local;

    const int   iy = ws_iy[y];
    const float ty = ws_ty[y];
    const int   c0 = ws_ix[x0];
    const int   ix = ws_ix[x];
    const float tx = ws_tx[x];

    int ncols = ws_ix[x0 + PTSB - 1] + 2 - c0;
    if (ncols > 16) ncols = 16;                 // safety cap (true inputs: ==16)
    const int crel = ix - c0;                   // 0..14 for true inputs

    // per-row span geometry (same for all 5 vars)
    const int se0 = (iy * WE + c0) * LL;        // first float of row-iy span
    const int se1 = se0 + WE37;                 // first float of row-(iy+1) span
    const int h0  = se0 & 3, h1 = se1 & 3;      // 16B-alignment head
    const int f00 = se0 - h0, f01 = se1 - h1;   // aligned float start
    const int n40 = (h0 + ncols * LL + 3) >> 2; // x4 slots needed, row 0
    const int n41 = (h1 + ncols * LL + 3) >> 2; // x4 slots needed, row 1

    // ---- stage 10 spans into LDS with dwordx4 direct-to-LDS loads ----
#pragma unroll
    for (int k = 0; k < NROUND; k++) {
        const int slot = tid + 256 * k;
        if (slot < NSLOT) {
            const int r  = slot / RSTR;         // range 0..9
            const int c  = slot - r * RSTR;     // x4 slot within range
            const int rr = r & 1;
            const int vv = r >> 1;
            const int n4 = rr ? n41 : n40;
            if (c < n4) {
                const int fbase = (rr ? f01 : f00) + 4 * c;
                const float* gp = ((vv == 0) ? u : (vv == 1) ? v
                                  : (vv == 2) ? w : (vv == 3) ? T : q) + fbase;
                float* lp = &s_stage[r * RFL + 4 * c];
                __builtin_amdgcn_global_load_lds(
                    (const __attribute__((address_space(1))) void*)gp,
                    (__attribute__((address_space(3))) void*)lp, 16, 0, 0);
            }
        }
    }

    // ps quad (tiny, broadcast per group; overlaps staging latency)
    const int b00 = iy * WE + ix;
    const float p00 = ps[b00], p01 = ps[b00 + 1];
    const float p10 = ps[b00 + WE], p11 = ps[b00 + WE + 1];

    // per-thread coefficients (L2-hot)
    const float ak = a_k[grp];
    const float bk = b_k[grp];

    __syncthreads();   // drains global_load_lds (compiler emits vmcnt(0))

    const float omty = 1.0f - ty, omtx = 1.0f - tx;
    const int   cb   = crel * LL;

    // ---- bilinear from staged LDS -> s_h (writer group == reader group) ----
#pragma unroll
    for (int vv = 0; vv < 5; vv++) {
        const float* r0 = &s_stage[(vv * 2 + 0) * RFL + h0 + cb];
        const float* r1 = &s_stage[(vv * 2 + 1) * RFL + h1 + cb];
        const float d00 = r0[grp], d01 = r0[grp + LL];
        const float d10 = r1[grp], d11 = r1[grp + LL];
        s_h[pt_local][vv * LL + grp] =
            omty * (omtx * d00 + tx * d01) + ty * (omtx * d10 + tx * d11);
    }
    if (grp < 25) {   // tail levels 32..36 for the 5 vars
        const int tvar = grp / 5;
        const int tl   = 32 + (grp - tvar * 5);
        const float* r0 = &s_stage[(tvar * 2 + 0) * RFL + h0 + cb];
        const float* r1 = &s_stage[(tvar * 2 + 1) * RFL + h1 + cb];
        const float d00 = r0[tl], d01 = r0[tl + LL];
        const float d10 = r1[tl], d11 = r1[tl + LL];
        s_h[pt_local][tvar * LL + tl] =
            omty * (omtx * d00 + tx * d01) + ty * (omtx * d10 + tx * d11);
    }

    // ---- phase 2: thread = (pt_local, k) ----
    const float ps_m = omty * (omtx * p00 + tx * p01) + ty * (omtx * p10 + tx * p11);
    if (grp == 0) out[OFF2 + pt] = fminf(fmaxf(ps_m, 30000.0f), 110000.0f);

    const float pm = ak + bk * ps_m;
    out[OFF1 + (size_t)pt * KK + grp] = pm;      // coalesced per 32-lane group

    const float lpm = logf(pm + EPSF);

    // linear count-scans == searchsorted(side='right') (independent ds_read_b64s)
    int nv = 0, ii = 0;
#pragma unroll
    for (int m = 0; m < LL; m++) {
        const float2 tb = s_tab[wv][m];
        nv += (tb.x <= ps_m) ? 1 : 0;
        if (m >= 1) ii += (tb.y <= lpm) ? 1 : 0;
    }
    int maxi = nv - 2;
    if (maxi < 0) maxi = 0;
    if (ii > maxi) ii = maxi;
    const bool invalid = (nv < 2);

    const float lx0 = s_tab[wv][ii].y;
    const float lx1 = s_tab[wv][ii + 1].y;
    const float t = (lpm - lx0) / (lx1 - lx0);

    __builtin_amdgcn_wave_barrier();   // order s_h writes before reads (no-op HW)

    const int half = lane >> 5;
    float* so = &s_out[wv][half * (KK * 5)];
#pragma unroll
    for (int var = 0; var < 5; var++) {
        const float g0 = s_h[pt_local][var * LL + ii];
        const float g1 = s_h[pt_local][var * LL + ii + 1];
        float o = g0 + t * (g1 - g0);
        if (invalid) o = 0.0f;                         // zero BEFORE clip (matches ref)
        if (var == 3) o = fminf(fmaxf(o, 150.0f), 350.0f);
        if (var == 4) o = fminf(fmaxf(o, 0.0f), 0.05f);
        so[grp * 5 + var] = o;                         // gcd(5,32)=1 -> conflict-free
    }

    __builtin_amdgcn_wave_barrier();

    // coalesced flush: wave's 2 points = 320 contiguous floats
    const size_t ob = (size_t)(pt0 + 2 * wv) * (KK * 5);
#pragma unroll
    for (int c = 0; c < 5; c++) {
        out[ob + lane + 64 * c] = s_out[wv][lane + 64 * c];
    }
}

extern "C" void kernel_launch(void* const* d_in, const int* in_sizes, int n_in,
                              void* d_out, int out_size, void* d_ws, size_t ws_size,
                              hipStream_t stream) {
    const float* u         = (const float*)d_in[0];
    const float* v         = (const float*)d_in[1];
    const float* w         = (const float*)d_in[2];
    const float* T         = (const float*)d_in[3];
    const float* q         = (const float*)d_in[4];
    const float* ps        = (const float*)d_in[5];
    const float* era5_lat  = (const float*)d_in[6];
    const float* era5_lon  = (const float*)d_in[7];
    const float* model_lat = (const float*)d_in[8];
    const float* model_lon = (const float*)d_in[9];
    const float* p_levels  = (const float*)d_in[10];
    const float* a_k       = (const float*)d_in[11];
    const float* b_k       = (const float*)d_in[12];

    float* wsf = (float*)d_ws;
    int*   ws_iy    = (int*)(wsf + WS_IY);
    float* ws_ty    = wsf + WS_TY;
    int*   ws_ix    = (int*)(wsf + WS_IX);
    float* ws_tx    = wsf + WS_TX;
    float* ws_logpe = wsf + WS_LOGPE;

    float* out = (float*)d_out;

    precompute_kernel<<<3, 256, 0, stream>>>(era5_lat, era5_lon, model_lat, model_lon,
                                             p_levels, ws_iy, ws_ty, ws_ix, ws_tx,
                                             ws_logpe);

    const int blocks = NPTS / PTSB;   // 8100
    fused_kernel<<<blocks, 256, 0, stream>>>(u, v, w, T, q, ps, p_levels, a_k, b_k,
                                             ws_iy, ws_ty, ws_ix, ws_tx, ws_logpe, out);
}